// Round 12
// baseline (120.340 us; speedup 1.0000x reference)
//
#include <hip/hip_runtime.h>

// Legendre2 via split-precision MFMA, v12: single-variable TLP probe on the
// R11 base (86.6 us, VGPR 116, zero spill): 768 threads = 12 waves = 3
// waves/SIMD (launch-bounds budget 512/3 ~ 170 regs holds the 116-reg live
// set; 1024-thr's 128 budget did not -- R4). 683 blocks, each wave owns
// exactly TWO contiguous 32-row tiles (8192 waves x 64 rows = N); the last
// block's surplus 4 waves retire after staging. Inner loop byte-identical
// to R11: a0/a1 k-half chain split + s_setprio around MFMA clusters +
// z-prefetch before the mat chain.
// N=524288, D=64, K=64, O=32, DEGREE=6.

typedef _Float16 f16x8 __attribute__((ext_vector_type(8)));
typedef short    s16x8 __attribute__((ext_vector_type(8)));
typedef float    f32x4 __attribute__((ext_vector_type(4)));

#define NN      524288
#define BLOCKS  683
#define THREADS 768
#define NWAVES  12
#define NTILES  16384                    // 32-row tiles
#define NACTIVE 8192                     // waves doing 2 tiles each

// LDS byte offsets
#define BH_OFF    0                      // 48 frags * 1 KB (f16 hi of A)
#define BL_OFF    49152                  // 48 frags * 1 KB (f16 lo of A)
#define CF_OFF    98304                  // 8 frags * 1 KB (bf16 h/l of C)
#define SCALE_OFF 106496                 // 384 f32 scales
#define SCR_OFF   108032                 // 12 waves * 4 KB transpose scratch
#define SMEM_BYTES (SCR_OFF + NWAVES * 4096)   // 157184 B (<= 160 KB)

__device__ __forceinline__ unsigned short f2bf(float x) {
    unsigned u = __builtin_bit_cast(unsigned, x);
    return (unsigned short)((u + 0x7FFFu + ((u >> 16) & 1u)) >> 16);
}

__global__ __launch_bounds__(THREADS) void leg_mfma(
    const float* __restrict__ z, const float* __restrict__ T,
    const float* __restrict__ Cm, const float* __restrict__ beta,
    float* __restrict__ out)
{
    extern __shared__ char smem[];
    float* scale_s = (float*)(smem + SCALE_OFF);
    const int tid  = (int)threadIdx.x;
    const int lane = tid & 63;
    const int wv   = tid >> 6;
    const int lrow = lane & 15;          // row (A-op) / col (C/D) index
    const int lhi  = lane >> 4;          // 0..3

    // ---------- phase A: per-row scales: j==0 -> 1, else coef_j / rowsum ----
    if (tid < 384) {
        const int mat = tid >> 6, kc = tid & 63;
        const float4* tr = (const float4*)(T + (size_t)((mat << 6) + kc) * 64);
        float s = 0.f;
        #pragma unroll
        for (int q = 0; q < 16; ++q) { float4 v = tr[q]; s += v.x + v.y + v.z + v.w; }
        float sc;
        if (mat == 0) sc = 1.f;
        else { const float fi = (float)(mat + 1); sc = (2.f * fi - 1.f) / fi / s; }
        scale_s[tid] = sc;
    }
    __syncthreads();

    // ---------- phase B: build B-operand frags of A (f16 hi/lo) -------------
    for (int g = tid; g < 3072; g += THREADS) {
        const int mat = g >> 9;
        const int s   = (g >> 8) & 1;
        const int f   = (g >> 6) & 3;
        const int l   = g & 63;
        const int kc  = (l & 15) + (f << 4);
        const int d0  = ((l >> 4) << 3) + (s << 5);
        const float sc = scale_s[(mat << 6) + kc];
        const float* src = T + (size_t)((mat << 6) + kc) * 64 + d0;
        const float4 v0 = *(const float4*)(src);
        const float4 v1 = *(const float4*)(src + 4);
        const float vv[8] = {v0.x, v0.y, v0.z, v0.w, v1.x, v1.y, v1.z, v1.w};
        f16x8 hi, lo;
        #pragma unroll
        for (int j = 0; j < 8; ++j) {
            const float x = vv[j] * sc;
            const _Float16 h = (_Float16)x;
            hi[j] = h;
            lo[j] = (_Float16)(x - (float)h);
        }
        const int fr = (((mat << 1) + s) << 2) + f;
        *(f16x8*)(smem + BH_OFF + fr * 1024 + l * 16) = hi;
        *(f16x8*)(smem + BL_OFF + fr * 1024 + l * 16) = lo;
    }
    // C-operand frags (bf16 hi/lo)
    if (tid < 512) {
        const int hl = (tid >> 8) & 1;
        const int s  = (tid >> 7) & 1;
        const int fo = (tid >> 6) & 1;
        const int l  = tid & 63;
        const int o  = (l & 15) + (fo << 4);
        const int k0 = ((l >> 4) << 3) + (s << 5);
        const float* src = Cm + (size_t)o * 64 + k0;
        const float4 v0 = *(const float4*)src;
        const float4 v1 = *(const float4*)(src + 4);
        const float vv[8] = {v0.x, v0.y, v0.z, v0.w, v1.x, v1.y, v1.z, v1.w};
        s16x8 fr;
        #pragma unroll
        for (int j = 0; j < 8; ++j) {
            const float x = vv[j];
            const unsigned short h = f2bf(x);
            if (hl) {
                const float hf = __builtin_bit_cast(float, (unsigned)h << 16);
                fr[j] = (short)f2bf(x - hf);
            } else {
                fr[j] = (short)h;
            }
        }
        *(s16x8*)(smem + CF_OFF + ((((hl << 1) + s) << 1) + fo) * 1024 + l * 16) = fr;
    }
    __syncthreads();

    // ---------- main: each active wave owns 64 rows = 2 x 32-row tiles ------
    const int gw = blockIdx.x * NWAVES + wv;
    if (gw >= NACTIVE) return;           // surplus waves (last block) retire
    const size_t rowbase = (size_t)gw * 64;
    float* scr = (float*)(smem + SCR_OFF + wv * 4096);

    const float beta0 = beta[lrow];
    const float beta1 = beta[16 + lrow];

    f16x8 zh[2][2], zl[2][2];

    // one Legendre level: PT := (a0+a1) * PC - b * PT; a0/a1 are independent
    // k-half chains of depth 3 (16 chains/level total).
    auto leg_step = [&](int mat, float b, f32x4 (&PC)[2][4], f32x4 (&PT)[2][4]) {
        __builtin_amdgcn_s_setprio(1);
        #pragma unroll
        for (int f = 0; f < 4; ++f) {
            const int fr0 = mat * 8 + f;       // s=0
            const int fr1 = mat * 8 + 4 + f;   // s=1
            const f16x8 bh0 = *(const f16x8*)(smem + BH_OFF + fr0 * 1024 + lane * 16);
            const f16x8 bl0 = *(const f16x8*)(smem + BL_OFF + fr0 * 1024 + lane * 16);
            const f16x8 bh1 = *(const f16x8*)(smem + BH_OFF + fr1 * 1024 + lane * 16);
            const f16x8 bl1 = *(const f16x8*)(smem + BL_OFF + fr1 * 1024 + lane * 16);
            #pragma unroll
            for (int t = 0; t < 2; ++t) {
                f32x4 a0 = {0.f, 0.f, 0.f, 0.f};
                f32x4 a1 = {0.f, 0.f, 0.f, 0.f};
                a0 = __builtin_amdgcn_mfma_f32_16x16x32_f16(zh[t][0], bh0, a0, 0, 0, 0);
                a1 = __builtin_amdgcn_mfma_f32_16x16x32_f16(zh[t][1], bh1, a1, 0, 0, 0);
                a0 = __builtin_amdgcn_mfma_f32_16x16x32_f16(zl[t][0], bh0, a0, 0, 0, 0);
                a1 = __builtin_amdgcn_mfma_f32_16x16x32_f16(zl[t][1], bh1, a1, 0, 0, 0);
                a0 = __builtin_amdgcn_mfma_f32_16x16x32_f16(zh[t][0], bl0, a0, 0, 0, 0);
                a1 = __builtin_amdgcn_mfma_f32_16x16x32_f16(zh[t][1], bl1, a1, 0, 0, 0);
                #pragma unroll
                for (int r = 0; r < 4; ++r)
                    PT[t][f][r] = (a0[r] + a1[r]) * PC[t][f][r] - b * PT[t][f][r];
            }
        }
        __builtin_amdgcn_s_setprio(0);
    };

    // prologue: load z for tile 0
    float4 zraw[2][4];
    #pragma unroll
    for (int t = 0; t < 2; ++t)
        #pragma unroll
        for (int s = 0; s < 2; ++s) {
            const float* p = z + (rowbase + t * 16 + lrow) * 64 + (s << 5) + (lhi << 3);
            zraw[t][2 * s]     = *(const float4*)(p);
            zraw[t][2 * s + 1] = *(const float4*)(p + 4);
        }

    for (int it = 0; it < 2; ++it) {
        // convert staged z to f16 hi/lo fragments
        #pragma unroll
        for (int t = 0; t < 2; ++t)
            #pragma unroll
            for (int s = 0; s < 2; ++s) {
                const float4 q0 = zraw[t][2 * s], q1 = zraw[t][2 * s + 1];
                const float vv[8] = {q0.x, q0.y, q0.z, q0.w, q1.x, q1.y, q1.z, q1.w};
                #pragma unroll
                for (int j = 0; j < 8; ++j) {
                    const _Float16 h = (_Float16)vv[j];
                    zh[t][s][j] = h;
                    zl[t][s][j] = (_Float16)(vv[j] - (float)h);
                }
            }
        // prefetch tile 1's z (in flight across the mat loop; dead before the
        // epilogue so it does not extend the epilogue live set)
        if (it < 1) {
            #pragma unroll
            for (int t = 0; t < 2; ++t)
                #pragma unroll
                for (int s = 0; s < 2; ++s) {
                    const float* p = z + (rowbase + 32 + t * 16 + lrow) * 64
                                       + (s << 5) + (lhi << 3);
                    zraw[t][2 * s]     = *(const float4*)(p);
                    zraw[t][2 * s + 1] = *(const float4*)(p + 4);
                }
        }

        // Legendre chain: pA = P1, pB = P2, then ping-pong; P6 ends in pB
        f32x4 pA[2][4], pB[2][4];
        // mat 0 -> pA  (P1) = a0 + a1
        __builtin_amdgcn_s_setprio(1);
        #pragma unroll
        for (int f = 0; f < 4; ++f) {
            const int fr0 = f, fr1 = 4 + f;
            const f16x8 bh0 = *(const f16x8*)(smem + BH_OFF + fr0 * 1024 + lane * 16);
            const f16x8 bl0 = *(const f16x8*)(smem + BL_OFF + fr0 * 1024 + lane * 16);
            const f16x8 bh1 = *(const f16x8*)(smem + BH_OFF + fr1 * 1024 + lane * 16);
            const f16x8 bl1 = *(const f16x8*)(smem + BL_OFF + fr1 * 1024 + lane * 16);
            #pragma unroll
            for (int t = 0; t < 2; ++t) {
                f32x4 a0 = {0.f, 0.f, 0.f, 0.f};
                f32x4 a1 = {0.f, 0.f, 0.f, 0.f};
                a0 = __builtin_amdgcn_mfma_f32_16x16x32_f16(zh[t][0], bh0, a0, 0, 0, 0);
                a1 = __builtin_amdgcn_mfma_f32_16x16x32_f16(zh[t][1], bh1, a1, 0, 0, 0);
                a0 = __builtin_amdgcn_mfma_f32_16x16x32_f16(zl[t][0], bh0, a0, 0, 0, 0);
                a1 = __builtin_amdgcn_mfma_f32_16x16x32_f16(zl[t][1], bh1, a1, 0, 0, 0);
                a0 = __builtin_amdgcn_mfma_f32_16x16x32_f16(zh[t][0], bl0, a0, 0, 0, 0);
                a1 = __builtin_amdgcn_mfma_f32_16x16x32_f16(zh[t][1], bl1, a1, 0, 0, 0);
                #pragma unroll
                for (int r = 0; r < 4; ++r)
                    pA[t][f][r] = a0[r] + a1[r];
            }
        }
        // mat 1 -> pB = W2*pA - 0.5  (P2; P0 = ones)
        #pragma unroll
        for (int f = 0; f < 4; ++f) {
            const int fr0 = 8 + f, fr1 = 12 + f;
            const f16x8 bh0 = *(const f16x8*)(smem + BH_OFF + fr0 * 1024 + lane * 16);
            const f16x8 bl0 = *(const f16x8*)(smem + BL_OFF + fr0 * 1024 + lane * 16);
            const f16x8 bh1 = *(const f16x8*)(smem + BH_OFF + fr1 * 1024 + lane * 16);
            const f16x8 bl1 = *(const f16x8*)(smem + BL_OFF + fr1 * 1024 + lane * 16);
            #pragma unroll
            for (int t = 0; t < 2; ++t) {
                f32x4 a0 = {0.f, 0.f, 0.f, 0.f};
                f32x4 a1 = {0.f, 0.f, 0.f, 0.f};
                a0 = __builtin_amdgcn_mfma_f32_16x16x32_f16(zh[t][0], bh0, a0, 0, 0, 0);
                a1 = __builtin_amdgcn_mfma_f32_16x16x32_f16(zh[t][1], bh1, a1, 0, 0, 0);
                a0 = __builtin_amdgcn_mfma_f32_16x16x32_f16(zl[t][0], bh0, a0, 0, 0, 0);
                a1 = __builtin_amdgcn_mfma_f32_16x16x32_f16(zl[t][1], bh1, a1, 0, 0, 0);
                a0 = __builtin_amdgcn_mfma_f32_16x16x32_f16(zh[t][0], bl0, a0, 0, 0, 0);
                a1 = __builtin_amdgcn_mfma_f32_16x16x32_f16(zh[t][1], bl1, a1, 0, 0, 0);
                #pragma unroll
                for (int r = 0; r < 4; ++r)
                    pB[t][f][r] = (a0[r] + a1[r]) * pA[t][f][r] - 0.5f;
            }
        }
        __builtin_amdgcn_s_setprio(0);
        leg_step(2, 2.f / 3.f, pB, pA);   // P3
        leg_step(3, 3.f / 4.f, pA, pB);   // P4
        leg_step(4, 4.f / 5.f, pB, pA);   // P5
        leg_step(5, 5.f / 6.f, pA, pB);   // P6 = pB

        // ---------------- epilogue: out = P6 @ C^T + beta -------------------
        s16x8 ch[2][2], cl[2][2];   // [s][fo]
        #pragma unroll
        for (int s = 0; s < 2; ++s)
            #pragma unroll
            for (int fo = 0; fo < 2; ++fo) {
                ch[s][fo] = *(const s16x8*)(smem + CF_OFF + ((s << 1) + fo) * 1024 + lane * 16);
                cl[s][fo] = *(const s16x8*)(smem + CF_OFF + (((2 + s) << 1) + fo) * 1024 + lane * 16);
            }
        #pragma unroll
        for (int t = 0; t < 2; ++t) {
            // transpose P6 (C/D layout) -> A-op layout via XOR-swizzled scratch
            #pragma unroll
            for (int f = 0; f < 4; ++f)
                #pragma unroll
                for (int r = 0; r < 4; ++r) {
                    const int row = lhi * 4 + r;
                    const int k   = (f << 4) + lrow;
                    const int g4  = (k >> 2) ^ row;            // group swizzle
                    scr[row * 64 + g4 * 4 + (k & 3)] = pB[t][f][r];
                }
            s16x8 p6h[2], p6l[2];
            #pragma unroll
            for (int s = 0; s < 2; ++s) {
                const int g0 = lhi * 2 + s * 8;
                const float4 q0 = *(const float4*)(scr + lrow * 64 + ((g0)     ^ lrow) * 4);
                const float4 q1 = *(const float4*)(scr + lrow * 64 + ((g0 + 1) ^ lrow) * 4);
                const float vv[8] = {q0.x, q0.y, q0.z, q0.w, q1.x, q1.y, q1.z, q1.w};
                #pragma unroll
                for (int j = 0; j < 8; ++j) {
                    const unsigned short h = f2bf(vv[j]);
                    const float hf = __builtin_bit_cast(float, (unsigned)h << 16);
                    p6h[s][j] = (short)h;
                    p6l[s][j] = (short)f2bf(vv[j] - hf);
                }
            }
            #pragma unroll
            for (int fo = 0; fo < 2; ++fo) {
                f32x4 o = {0.f, 0.f, 0.f, 0.f};
                o = __builtin_amdgcn_mfma_f32_16x16x32_bf16(p6h[0], ch[0][fo], o, 0, 0, 0);
                o = __builtin_amdgcn_mfma_f32_16x16x32_bf16(p6l[0], ch[0][fo], o, 0, 0, 0);
                o = __builtin_amdgcn_mfma_f32_16x16x32_bf16(p6h[0], cl[0][fo], o, 0, 0, 0);
                o = __builtin_amdgcn_mfma_f32_16x16x32_bf16(p6h[1], ch[1][fo], o, 0, 0, 0);
                o = __builtin_amdgcn_mfma_f32_16x16x32_bf16(p6l[1], ch[1][fo], o, 0, 0, 0);
                o = __builtin_amdgcn_mfma_f32_16x16x32_bf16(p6h[1], cl[1][fo], o, 0, 0, 0);
                const float bb = fo ? beta1 : beta0;
                const size_t r0 = rowbase + (size_t)it * 32 + t * 16 + lhi * 4;
                #pragma unroll
                for (int r = 0; r < 4; ++r)
                    out[(r0 + r) * 32 + (fo << 4) + lrow] = o[r] + bb;
            }
        }
    }
}

extern "C" void kernel_launch(void* const* d_in, const int* in_sizes, int n_in,
                              void* d_out, int out_size, void* d_ws, size_t ws_size,
                              hipStream_t stream) {
    const float* z    = (const float*)d_in[0];
    const float* T    = (const float*)d_in[1];
    const float* C    = (const float*)d_in[2];
    const float* beta = (const float*)d_in[3];
    float* out = (float*)d_out;
    (void)in_sizes; (void)n_in; (void)out_size; (void)d_ws; (void)ws_size;

    hipFuncSetAttribute((const void*)leg_mfma,
                        hipFuncAttributeMaxDynamicSharedMemorySize, SMEM_BYTES);
    leg_mfma<<<BLOCKS, THREADS, SMEM_BYTES, stream>>>(z, T, C, beta, out);
}

// Round 13
// 58.803 us; speedup vs baseline: 2.0465x; 2.0465x over previous
//
#include <hip/hip_runtime.h>

// Legendre2 v13: SINGLE-TERM f16 main chain. Harness compares at bf16
// granularity (absmax floor 2^22 = 1 ulp for both f32 and f16-3-term
// kernels; threshold allows ~13 ulp) -> the hi/lo 3-term split is overkill.
// Main chain: W = zh @ Ah^T, one f16 MFMA per k-half (16 MFMA/level, was
// 48). Epilogue keeps 3-term bf16 (only 12 MFMAs, insurance on the last
// rounding). Structure = R11 (best, 86.6us): 512 thr, 8 waves x 256 rows,
// k-half split accumulators, setprio on MFMA clusters, z-prefetch before
// the mat chain. LDS: A-hi 48K + C 8K + scales + 8x4K scratch = 90 KB.
// N=524288, D=64, K=64, O=32, DEGREE=6.

typedef _Float16 f16x8 __attribute__((ext_vector_type(8)));
typedef short    s16x8 __attribute__((ext_vector_type(8)));
typedef float    f32x4 __attribute__((ext_vector_type(4)));

#define NN      524288
#define BLOCKS  256
#define THREADS 512
#define NWAVES  8

// LDS byte offsets
#define BH_OFF    0                      // 48 frags * 1 KB (f16 hi of A)
#define CF_OFF    49152                  // 8 frags * 1 KB (bf16 h/l of C)
#define SCALE_OFF 57344                  // 384 f32 scales
#define SCR_OFF   58880                  // 8 waves * 4 KB transpose scratch
#define SMEM_BYTES (SCR_OFF + NWAVES * 4096)   // 91648 B

__device__ __forceinline__ unsigned short f2bf(float x) {
    unsigned u = __builtin_bit_cast(unsigned, x);
    return (unsigned short)((u + 0x7FFFu + ((u >> 16) & 1u)) >> 16);
}

__global__ __launch_bounds__(THREADS) void leg_mfma(
    const float* __restrict__ z, const float* __restrict__ T,
    const float* __restrict__ Cm, const float* __restrict__ beta,
    float* __restrict__ out)
{
    extern __shared__ char smem[];
    float* scale_s = (float*)(smem + SCALE_OFF);
    const int tid  = (int)threadIdx.x;
    const int lane = tid & 63;
    const int wv   = tid >> 6;
    const int lrow = lane & 15;          // row (A-op) / col (C/D) index
    const int lhi  = lane >> 4;          // 0..3

    // ---------- phase A: per-row scales: j==0 -> 1, else coef_j / rowsum ----
    if (tid < 384) {
        const int mat = tid >> 6, kc = tid & 63;
        const float4* tr = (const float4*)(T + (size_t)((mat << 6) + kc) * 64);
        float s = 0.f;
        #pragma unroll
        for (int q = 0; q < 16; ++q) { float4 v = tr[q]; s += v.x + v.y + v.z + v.w; }
        float sc;
        if (mat == 0) sc = 1.f;
        else { const float fi = (float)(mat + 1); sc = (2.f * fi - 1.f) / fi / s; }
        scale_s[tid] = sc;
    }
    __syncthreads();

    // ---------- phase B: build B-operand frags of A (f16, single term) ------
    for (int g = tid; g < 3072; g += THREADS) {
        const int mat = g >> 9;
        const int s   = (g >> 8) & 1;
        const int f   = (g >> 6) & 3;
        const int l   = g & 63;
        const int kc  = (l & 15) + (f << 4);
        const int d0  = ((l >> 4) << 3) + (s << 5);
        const float sc = scale_s[(mat << 6) + kc];
        const float* src = T + (size_t)((mat << 6) + kc) * 64 + d0;
        const float4 v0 = *(const float4*)(src);
        const float4 v1 = *(const float4*)(src + 4);
        const float vv[8] = {v0.x, v0.y, v0.z, v0.w, v1.x, v1.y, v1.z, v1.w};
        f16x8 hi;
        #pragma unroll
        for (int j = 0; j < 8; ++j) hi[j] = (_Float16)(vv[j] * sc);
        const int fr = (((mat << 1) + s) << 2) + f;
        *(f16x8*)(smem + BH_OFF + fr * 1024 + l * 16) = hi;
    }
    // C-operand frags (bf16 hi/lo) -- epilogue keeps 3-term
    {
        const int hl = (tid >> 8) & 1;
        const int s  = (tid >> 7) & 1;
        const int fo = (tid >> 6) & 1;
        const int l  = tid & 63;
        const int o  = (l & 15) + (fo << 4);
        const int k0 = ((l >> 4) << 3) + (s << 5);
        const float* src = Cm + (size_t)o * 64 + k0;
        const float4 v0 = *(const float4*)src;
        const float4 v1 = *(const float4*)(src + 4);
        const float vv[8] = {v0.x, v0.y, v0.z, v0.w, v1.x, v1.y, v1.z, v1.w};
        s16x8 fr;
        #pragma unroll
        for (int j = 0; j < 8; ++j) {
            const float x = vv[j];
            const unsigned short h = f2bf(x);
            if (hl) {
                const float hf = __builtin_bit_cast(float, (unsigned)h << 16);
                fr[j] = (short)f2bf(x - hf);
            } else {
                fr[j] = (short)h;
            }
        }
        *(s16x8*)(smem + CF_OFF + ((((hl << 1) + s) << 1) + fo) * 1024 + l * 16) = fr;
    }
    __syncthreads();

    // ---------- main: each wave owns 256 rows, 8 iters of 32 rows -----------
    const int    gw      = blockIdx.x * NWAVES + wv;
    const size_t rowbase = (size_t)gw * 256;
    float* scr = (float*)(smem + SCR_OFF + wv * 4096);

    const float beta0 = beta[lrow];
    const float beta1 = beta[16 + lrow];

    f16x8 zh[2][2];

    // one Legendre level: PT := (a0+a1) * PC - b * PT; a0/a1 are independent
    // single-MFMA k-half chains.
    auto leg_step = [&](int mat, float b, f32x4 (&PC)[2][4], f32x4 (&PT)[2][4]) {
        __builtin_amdgcn_s_setprio(1);
        #pragma unroll
        for (int f = 0; f < 4; ++f) {
            const int fr0 = mat * 8 + f;       // s=0
            const int fr1 = mat * 8 + 4 + f;   // s=1
            const f16x8 bh0 = *(const f16x8*)(smem + BH_OFF + fr0 * 1024 + lane * 16);
            const f16x8 bh1 = *(const f16x8*)(smem + BH_OFF + fr1 * 1024 + lane * 16);
            #pragma unroll
            for (int t = 0; t < 2; ++t) {
                f32x4 a0 = {0.f, 0.f, 0.f, 0.f};
                f32x4 a1 = {0.f, 0.f, 0.f, 0.f};
                a0 = __builtin_amdgcn_mfma_f32_16x16x32_f16(zh[t][0], bh0, a0, 0, 0, 0);
                a1 = __builtin_amdgcn_mfma_f32_16x16x32_f16(zh[t][1], bh1, a1, 0, 0, 0);
                #pragma unroll
                for (int r = 0; r < 4; ++r)
                    PT[t][f][r] = (a0[r] + a1[r]) * PC[t][f][r] - b * PT[t][f][r];
            }
        }
        __builtin_amdgcn_s_setprio(0);
    };

    // prologue: load z for iter 0
    float4 zraw[2][4];
    #pragma unroll
    for (int t = 0; t < 2; ++t)
        #pragma unroll
        for (int s = 0; s < 2; ++s) {
            const float* p = z + (rowbase + t * 16 + lrow) * 64 + (s << 5) + (lhi << 3);
            zraw[t][2 * s]     = *(const float4*)(p);
            zraw[t][2 * s + 1] = *(const float4*)(p + 4);
        }

    for (int it = 0; it < 8; ++it) {
        // convert staged z to f16 fragments (single term)
        #pragma unroll
        for (int t = 0; t < 2; ++t)
            #pragma unroll
            for (int s = 0; s < 2; ++s) {
                const float4 q0 = zraw[t][2 * s], q1 = zraw[t][2 * s + 1];
                const float vv[8] = {q0.x, q0.y, q0.z, q0.w, q1.x, q1.y, q1.z, q1.w};
                #pragma unroll
                for (int j = 0; j < 8; ++j) zh[t][s][j] = (_Float16)vv[j];
            }
        // prefetch next iter's z (in flight across the mat loop; dead before
        // the epilogue so it does not extend the epilogue live set)
        if (it < 7) {
            #pragma unroll
            for (int t = 0; t < 2; ++t)
                #pragma unroll
                for (int s = 0; s < 2; ++s) {
                    const float* p = z + (rowbase + (it + 1) * 32 + t * 16 + lrow) * 64
                                       + (s << 5) + (lhi << 3);
                    zraw[t][2 * s]     = *(const float4*)(p);
                    zraw[t][2 * s + 1] = *(const float4*)(p + 4);
                }
        }

        // Legendre chain: pA = P1, pB = P2, then ping-pong; P6 ends in pB
        f32x4 pA[2][4], pB[2][4];
        // mat 0 -> pA  (P1) = a0 + a1
        __builtin_amdgcn_s_setprio(1);
        #pragma unroll
        for (int f = 0; f < 4; ++f) {
            const int fr0 = f, fr1 = 4 + f;
            const f16x8 bh0 = *(const f16x8*)(smem + BH_OFF + fr0 * 1024 + lane * 16);
            const f16x8 bh1 = *(const f16x8*)(smem + BH_OFF + fr1 * 1024 + lane * 16);
            #pragma unroll
            for (int t = 0; t < 2; ++t) {
                f32x4 a0 = {0.f, 0.f, 0.f, 0.f};
                f32x4 a1 = {0.f, 0.f, 0.f, 0.f};
                a0 = __builtin_amdgcn_mfma_f32_16x16x32_f16(zh[t][0], bh0, a0, 0, 0, 0);
                a1 = __builtin_amdgcn_mfma_f32_16x16x32_f16(zh[t][1], bh1, a1, 0, 0, 0);
                #pragma unroll
                for (int r = 0; r < 4; ++r)
                    pA[t][f][r] = a0[r] + a1[r];
            }
        }
        // mat 1 -> pB = W2*pA - 0.5  (P2; P0 = ones)
        #pragma unroll
        for (int f = 0; f < 4; ++f) {
            const int fr0 = 8 + f, fr1 = 12 + f;
            const f16x8 bh0 = *(const f16x8*)(smem + BH_OFF + fr0 * 1024 + lane * 16);
            const f16x8 bh1 = *(const f16x8*)(smem + BH_OFF + fr1 * 1024 + lane * 16);
            #pragma unroll
            for (int t = 0; t < 2; ++t) {
                f32x4 a0 = {0.f, 0.f, 0.f, 0.f};
                f32x4 a1 = {0.f, 0.f, 0.f, 0.f};
                a0 = __builtin_amdgcn_mfma_f32_16x16x32_f16(zh[t][0], bh0, a0, 0, 0, 0);
                a1 = __builtin_amdgcn_mfma_f32_16x16x32_f16(zh[t][1], bh1, a1, 0, 0, 0);
                #pragma unroll
                for (int r = 0; r < 4; ++r)
                    pB[t][f][r] = (a0[r] + a1[r]) * pA[t][f][r] - 0.5f;
            }
        }
        __builtin_amdgcn_s_setprio(0);
        leg_step(2, 2.f / 3.f, pB, pA);   // P3
        leg_step(3, 3.f / 4.f, pA, pB);   // P4
        leg_step(4, 4.f / 5.f, pB, pA);   // P5
        leg_step(5, 5.f / 6.f, pA, pB);   // P6 = pB

        // ---------------- epilogue: out = P6 @ C^T + beta -------------------
        s16x8 ch[2][2], cl[2][2];   // [s][fo]
        #pragma unroll
        for (int s = 0; s < 2; ++s)
            #pragma unroll
            for (int fo = 0; fo < 2; ++fo) {
                ch[s][fo] = *(const s16x8*)(smem + CF_OFF + ((s << 1) + fo) * 1024 + lane * 16);
                cl[s][fo] = *(const s16x8*)(smem + CF_OFF + (((2 + s) << 1) + fo) * 1024 + lane * 16);
            }
        #pragma unroll
        for (int t = 0; t < 2; ++t) {
            // transpose P6 (C/D layout) -> A-op layout via XOR-swizzled scratch
            #pragma unroll
            for (int f = 0; f < 4; ++f)
                #pragma unroll
                for (int r = 0; r < 4; ++r) {
                    const int row = lhi * 4 + r;
                    const int k   = (f << 4) + lrow;
                    const int g4  = (k >> 2) ^ row;            // group swizzle
                    scr[row * 64 + g4 * 4 + (k & 3)] = pB[t][f][r];
                }
            s16x8 p6h[2], p6l[2];
            #pragma unroll
            for (int s = 0; s < 2; ++s) {
                const int g0 = lhi * 2 + s * 8;
                const float4 q0 = *(const float4*)(scr + lrow * 64 + ((g0)     ^ lrow) * 4);
                const float4 q1 = *(const float4*)(scr + lrow * 64 + ((g0 + 1) ^ lrow) * 4);
                const float vv[8] = {q0.x, q0.y, q0.z, q0.w, q1.x, q1.y, q1.z, q1.w};
                #pragma unroll
                for (int j = 0; j < 8; ++j) {
                    const unsigned short h = f2bf(vv[j]);
                    const float hf = __builtin_bit_cast(float, (unsigned)h << 16);
                    p6h[s][j] = (short)h;
                    p6l[s][j] = (short)f2bf(vv[j] - hf);
                }
            }
            #pragma unroll
            for (int fo = 0; fo < 2; ++fo) {
                f32x4 o = {0.f, 0.f, 0.f, 0.f};
                o = __builtin_amdgcn_mfma_f32_16x16x32_bf16(p6h[0], ch[0][fo], o, 0, 0, 0);
                o = __builtin_amdgcn_mfma_f32_16x16x32_bf16(p6l[0], ch[0][fo], o, 0, 0, 0);
                o = __builtin_amdgcn_mfma_f32_16x16x32_bf16(p6h[0], cl[0][fo], o, 0, 0, 0);
                o = __builtin_amdgcn_mfma_f32_16x16x32_bf16(p6h[1], ch[1][fo], o, 0, 0, 0);
                o = __builtin_amdgcn_mfma_f32_16x16x32_bf16(p6l[1], ch[1][fo], o, 0, 0, 0);
                o = __builtin_amdgcn_mfma_f32_16x16x32_bf16(p6h[1], cl[1][fo], o, 0, 0, 0);
                const float bb = fo ? beta1 : beta0;
                const size_t r0 = rowbase + (size_t)it * 32 + t * 16 + lhi * 4;
                #pragma unroll
                for (int r = 0; r < 4; ++r)
                    out[(r0 + r) * 32 + (fo << 4) + lrow] = o[r] + bb;
            }
        }
    }
}

extern "C" void kernel_launch(void* const* d_in, const int* in_sizes, int n_in,
                              void* d_out, int out_size, void* d_ws, size_t ws_size,
                              hipStream_t stream) {
    const float* z    = (const float*)d_in[0];
    const float* T    = (const float*)d_in[1];
    const float* C    = (const float*)d_in[2];
    const float* beta = (const float*)d_in[3];
    float* out = (float*)d_out;
    (void)in_sizes; (void)n_in; (void)out_size; (void)d_ws; (void)ws_size;

    hipFuncSetAttribute((const void*)leg_mfma,
                        hipFuncAttributeMaxDynamicSharedMemorySize, SMEM_BYTES);
    leg_mfma<<<BLOCKS, THREADS, SMEM_BYTES, stream>>>(z, T, C, beta, out);
}

// Round 14
// 51.351 us; speedup vs baseline: 2.3435x; 1.1451x over previous
//
#include <hip/hip_runtime.h>

// Legendre2 v14: VALU trim on v13 (58.8us). Two changes:
//  (1) chained k-half MFMA: a = mfma(zh1,bh1, mfma(zh0,bh0,0)) -- deletes the
//      32 a0+a1 adds per level (192 VALU/iter); depth-2 chains x8/level.
//  (2) single-term bf16 epilogue: o = p6h @ ch only (drop p6l, cl) -- deletes
//      ~250 VALU/iter of hi/lo splitting + 16 MFMAs; C table 4KB.
//      Error budget: current absmax 2^23=8.4e6; bf16 single-term adds ~3e6
//      random -> ~9e6 total, threshold 5.4e7.
// Structure = v13: 512 thr, 8 waves x 256 rows, full A-hi table in LDS,
// setprio on MFMA clusters, z-prefetch before the mat chain.
// N=524288, D=64, K=64, O=32, DEGREE=6.

typedef _Float16 f16x8 __attribute__((ext_vector_type(8)));
typedef short    s16x8 __attribute__((ext_vector_type(8)));
typedef float    f32x4 __attribute__((ext_vector_type(4)));

#define NN      524288
#define BLOCKS  256
#define THREADS 512
#define NWAVES  8

// LDS byte offsets
#define BH_OFF    0                      // 48 frags * 1 KB (f16 of A)
#define CF_OFF    49152                  // 4 frags * 1 KB (bf16 hi of C)
#define SCALE_OFF 53248                  // 384 f32 scales
#define SCR_OFF   54784                  // 8 waves * 4 KB transpose scratch
#define SMEM_BYTES (SCR_OFF + NWAVES * 4096)   // 87552 B

__device__ __forceinline__ unsigned short f2bf(float x) {
    unsigned u = __builtin_bit_cast(unsigned, x);
    return (unsigned short)((u + 0x7FFFu + ((u >> 16) & 1u)) >> 16);
}

__global__ __launch_bounds__(THREADS) void leg_mfma(
    const float* __restrict__ z, const float* __restrict__ T,
    const float* __restrict__ Cm, const float* __restrict__ beta,
    float* __restrict__ out)
{
    extern __shared__ char smem[];
    float* scale_s = (float*)(smem + SCALE_OFF);
    const int tid  = (int)threadIdx.x;
    const int lane = tid & 63;
    const int wv   = tid >> 6;
    const int lrow = lane & 15;          // row (A-op) / col (C/D) index
    const int lhi  = lane >> 4;          // 0..3

    // ---------- phase A: per-row scales: j==0 -> 1, else coef_j / rowsum ----
    if (tid < 384) {
        const int mat = tid >> 6, kc = tid & 63;
        const float4* tr = (const float4*)(T + (size_t)((mat << 6) + kc) * 64);
        float s = 0.f;
        #pragma unroll
        for (int q = 0; q < 16; ++q) { float4 v = tr[q]; s += v.x + v.y + v.z + v.w; }
        float sc;
        if (mat == 0) sc = 1.f;
        else { const float fi = (float)(mat + 1); sc = (2.f * fi - 1.f) / fi / s; }
        scale_s[tid] = sc;
    }
    __syncthreads();

    // ---------- phase B: build B-operand frags of A (f16, single term) ------
    for (int g = tid; g < 3072; g += THREADS) {
        const int mat = g >> 9;
        const int s   = (g >> 8) & 1;
        const int f   = (g >> 6) & 3;
        const int l   = g & 63;
        const int kc  = (l & 15) + (f << 4);
        const int d0  = ((l >> 4) << 3) + (s << 5);
        const float sc = scale_s[(mat << 6) + kc];
        const float* src = T + (size_t)((mat << 6) + kc) * 64 + d0;
        const float4 v0 = *(const float4*)(src);
        const float4 v1 = *(const float4*)(src + 4);
        const float vv[8] = {v0.x, v0.y, v0.z, v0.w, v1.x, v1.y, v1.z, v1.w};
        f16x8 hi;
        #pragma unroll
        for (int j = 0; j < 8; ++j) hi[j] = (_Float16)(vv[j] * sc);
        const int fr = (((mat << 1) + s) << 2) + f;
        *(f16x8*)(smem + BH_OFF + fr * 1024 + l * 16) = hi;
    }
    // C-operand frags (bf16 single-term): frag(s,fo): lane l supplies
    // C2[k=32s+(l>>4)*8+j][o=(l&15)+16fo] = C[o][k].
    if (tid < 256) {
        const int s  = (tid >> 7) & 1;
        const int fo = (tid >> 6) & 1;
        const int l  = tid & 63;
        const int o  = (l & 15) + (fo << 4);
        const int k0 = ((l >> 4) << 3) + (s << 5);
        const float* src = Cm + (size_t)o * 64 + k0;
        const float4 v0 = *(const float4*)src;
        const float4 v1 = *(const float4*)(src + 4);
        const float vv[8] = {v0.x, v0.y, v0.z, v0.w, v1.x, v1.y, v1.z, v1.w};
        s16x8 fr;
        #pragma unroll
        for (int j = 0; j < 8; ++j) fr[j] = (short)f2bf(vv[j]);
        *(s16x8*)(smem + CF_OFF + ((s << 1) + fo) * 1024 + l * 16) = fr;
    }
    __syncthreads();

    // ---------- main: each wave owns 256 rows, 8 iters of 32 rows -----------
    const int    gw      = blockIdx.x * NWAVES + wv;
    const size_t rowbase = (size_t)gw * 256;
    float* scr = (float*)(smem + SCR_OFF + wv * 4096);

    const float beta0 = beta[lrow];
    const float beta1 = beta[16 + lrow];

    f16x8 zh[2][2];

    // one Legendre level: PT := a * PC - b * PT, a = chained k-half MFMAs
    auto leg_step = [&](int mat, float b, f32x4 (&PC)[2][4], f32x4 (&PT)[2][4]) {
        __builtin_amdgcn_s_setprio(1);
        #pragma unroll
        for (int f = 0; f < 4; ++f) {
            const int fr0 = mat * 8 + f;       // s=0
            const int fr1 = mat * 8 + 4 + f;   // s=1
            const f16x8 bh0 = *(const f16x8*)(smem + BH_OFF + fr0 * 1024 + lane * 16);
            const f16x8 bh1 = *(const f16x8*)(smem + BH_OFF + fr1 * 1024 + lane * 16);
            #pragma unroll
            for (int t = 0; t < 2; ++t) {
                f32x4 a = {0.f, 0.f, 0.f, 0.f};
                a = __builtin_amdgcn_mfma_f32_16x16x32_f16(zh[t][0], bh0, a, 0, 0, 0);
                a = __builtin_amdgcn_mfma_f32_16x16x32_f16(zh[t][1], bh1, a, 0, 0, 0);
                #pragma unroll
                for (int r = 0; r < 4; ++r)
                    PT[t][f][r] = a[r] * PC[t][f][r] - b * PT[t][f][r];
            }
        }
        __builtin_amdgcn_s_setprio(0);
    };

    // prologue: load z for iter 0
    float4 zraw[2][4];
    #pragma unroll
    for (int t = 0; t < 2; ++t)
        #pragma unroll
        for (int s = 0; s < 2; ++s) {
            const float* p = z + (rowbase + t * 16 + lrow) * 64 + (s << 5) + (lhi << 3);
            zraw[t][2 * s]     = *(const float4*)(p);
            zraw[t][2 * s + 1] = *(const float4*)(p + 4);
        }

    for (int it = 0; it < 8; ++it) {
        // convert staged z to f16 fragments
        #pragma unroll
        for (int t = 0; t < 2; ++t)
            #pragma unroll
            for (int s = 0; s < 2; ++s) {
                const float4 q0 = zraw[t][2 * s], q1 = zraw[t][2 * s + 1];
                const float vv[8] = {q0.x, q0.y, q0.z, q0.w, q1.x, q1.y, q1.z, q1.w};
                #pragma unroll
                for (int j = 0; j < 8; ++j) zh[t][s][j] = (_Float16)vv[j];
            }
        // prefetch next iter's z (in flight across the mat loop)
        if (it < 7) {
            #pragma unroll
            for (int t = 0; t < 2; ++t)
                #pragma unroll
                for (int s = 0; s < 2; ++s) {
                    const float* p = z + (rowbase + (it + 1) * 32 + t * 16 + lrow) * 64
                                       + (s << 5) + (lhi << 3);
                    zraw[t][2 * s]     = *(const float4*)(p);
                    zraw[t][2 * s + 1] = *(const float4*)(p + 4);
                }
        }

        // Legendre chain: pA = P1, pB = P2, then ping-pong; P6 ends in pB
        f32x4 pA[2][4], pB[2][4];
        // mat 0 -> pA  (P1), chained
        __builtin_amdgcn_s_setprio(1);
        #pragma unroll
        for (int f = 0; f < 4; ++f) {
            const int fr0 = f, fr1 = 4 + f;
            const f16x8 bh0 = *(const f16x8*)(smem + BH_OFF + fr0 * 1024 + lane * 16);
            const f16x8 bh1 = *(const f16x8*)(smem + BH_OFF + fr1 * 1024 + lane * 16);
            #pragma unroll
            for (int t = 0; t < 2; ++t) {
                f32x4 a = {0.f, 0.f, 0.f, 0.f};
                a = __builtin_amdgcn_mfma_f32_16x16x32_f16(zh[t][0], bh0, a, 0, 0, 0);
                a = __builtin_amdgcn_mfma_f32_16x16x32_f16(zh[t][1], bh1, a, 0, 0, 0);
                pA[t][f] = a;
            }
        }
        // mat 1 -> pB = W2*pA - 0.5  (P2; P0 = ones)
        #pragma unroll
        for (int f = 0; f < 4; ++f) {
            const int fr0 = 8 + f, fr1 = 12 + f;
            const f16x8 bh0 = *(const f16x8*)(smem + BH_OFF + fr0 * 1024 + lane * 16);
            const f16x8 bh1 = *(const f16x8*)(smem + BH_OFF + fr1 * 1024 + lane * 16);
            #pragma unroll
            for (int t = 0; t < 2; ++t) {
                f32x4 a = {0.f, 0.f, 0.f, 0.f};
                a = __builtin_amdgcn_mfma_f32_16x16x32_f16(zh[t][0], bh0, a, 0, 0, 0);
                a = __builtin_amdgcn_mfma_f32_16x16x32_f16(zh[t][1], bh1, a, 0, 0, 0);
                #pragma unroll
                for (int r = 0; r < 4; ++r)
                    pB[t][f][r] = a[r] * pA[t][f][r] - 0.5f;
            }
        }
        __builtin_amdgcn_s_setprio(0);
        leg_step(2, 2.f / 3.f, pB, pA);   // P3
        leg_step(3, 3.f / 4.f, pA, pB);   // P4
        leg_step(4, 4.f / 5.f, pB, pA);   // P5
        leg_step(5, 5.f / 6.f, pA, pB);   // P6 = pB

        // ---------------- epilogue: out = P6 @ C^T + beta (single-term) -----
        s16x8 ch[2][2];   // [s][fo]
        #pragma unroll
        for (int s = 0; s < 2; ++s)
            #pragma unroll
            for (int fo = 0; fo < 2; ++fo)
                ch[s][fo] = *(const s16x8*)(smem + CF_OFF + ((s << 1) + fo) * 1024 + lane * 16);
        #pragma unroll
        for (int t = 0; t < 2; ++t) {
            // transpose P6 (C/D layout) -> A-op layout via XOR-swizzled scratch
            #pragma unroll
            for (int f = 0; f < 4; ++f)
                #pragma unroll
                for (int r = 0; r < 4; ++r) {
                    const int row = lhi * 4 + r;
                    const int k   = (f << 4) + lrow;
                    const int g4  = (k >> 2) ^ row;            // group swizzle
                    scr[row * 64 + g4 * 4 + (k & 3)] = pB[t][f][r];
                }
            s16x8 p6h[2];
            #pragma unroll
            for (int s = 0; s < 2; ++s) {
                const int g0 = lhi * 2 + s * 8;
                const float4 q0 = *(const float4*)(scr + lrow * 64 + ((g0)     ^ lrow) * 4);
                const float4 q1 = *(const float4*)(scr + lrow * 64 + ((g0 + 1) ^ lrow) * 4);
                const float vv[8] = {q0.x, q0.y, q0.z, q0.w, q1.x, q1.y, q1.z, q1.w};
                #pragma unroll
                for (int j = 0; j < 8; ++j) p6h[s][j] = (short)f2bf(vv[j]);
            }
            #pragma unroll
            for (int fo = 0; fo < 2; ++fo) {
                f32x4 o = {0.f, 0.f, 0.f, 0.f};
                o = __builtin_amdgcn_mfma_f32_16x16x32_bf16(p6h[0], ch[0][fo], o, 0, 0, 0);
                o = __builtin_amdgcn_mfma_f32_16x16x32_bf16(p6h[1], ch[1][fo], o, 0, 0, 0);
                const float bb = fo ? beta1 : beta0;
                const size_t r0 = rowbase + (size_t)it * 32 + t * 16 + lhi * 4;
                #pragma unroll
                for (int r = 0; r < 4; ++r)
                    out[(r0 + r) * 32 + (fo << 4) + lrow] = o[r] + bb;
            }
        }
    }
}

extern "C" void kernel_launch(void* const* d_in, const int* in_sizes, int n_in,
                              void* d_out, int out_size, void* d_ws, size_t ws_size,
                              hipStream_t stream) {
    const float* z    = (const float*)d_in[0];
    const float* T    = (const float*)d_in[1];
    const float* C    = (const float*)d_in[2];
    const float* beta = (const float*)d_in[3];
    float* out = (float*)d_out;
    (void)in_sizes; (void)n_in; (void)out_size; (void)d_ws; (void)ws_size;

    hipFuncSetAttribute((const void*)leg_mfma,
                        hipFuncAttributeMaxDynamicSharedMemorySize, SMEM_BYTES);
    leg_mfma<<<BLOCKS, THREADS, SMEM_BYTES, stream>>>(z, T, C, beta, out);
}